// Round 3
// baseline (757.822 us; speedup 1.0000x reference)
//
#include <hip/hip_runtime.h>
#include <stdint.h>

// Softmax-Viterbi forward, 1024x1024, S=4.
// R11: move the P-feed (diverged A/theta gather + exp2) OFF the 16 pipeline
// CUs. Evidence (R10): doubling producer waves on-CU changed nothing ->
// strip throughput is bound by shared per-CU resources: ~1280 TA addr-cycles
// per half-chunk for the 64-line-diverged gathers + ~400cy trans-pipe exp2,
// forcing T_step ~790cy while the chain's true dep-chain is ~10 VALU ops.
// New structure (grid 256, 384 thr):
//   blocks 0..15  : pipeline. wave0 chain (math unchanged from R10),
//                   waves1-3 loaders (global ring -> LDS, coherent+coalesced),
//                   wave4 out-comms, wave5 in-comms (unchanged).
//   blocks 16..255: producers, 15 per strip (bid%8 lands on the strip's XCD
//                   as a perf heuristic only). 4 waves, one per tau of the hc:
//                   diverged gather + theta-folded exp2 -> global P ring
//                   (depth 32 hc/strip, coherent stores, vmcnt(0)+flag).
// Correctness does not depend on XCD mapping: all cross-block traffic uses
// the proven agent-scope coherent load/store + vmcnt(0)+flag pattern.
// ws: records 512K | rec flags 2K | chain progress | ring flags 32K | ring 8M.

#define MM    1024
#define LOG2E 1.4426950408889634f
#define LN2f  0.6931471805599453f
#define NEGI  (-1073741824)
#define CH    8
#define NCH   136
#define HCT   (NCH*2)                // 272 half-chunks, 4 steps each
#define DEPTH 32                     // global P-ring depth in half-chunks
#define PPS   15                     // producer blocks per strip

#define F_RIN   0
#define F_CDONE 1
#define F_OPUB  2
#define F_PD    4                    // F_PD + (h&7): LDS slot ready flags

__device__ __forceinline__ float ld_cohf(const float* p) {
    return __hip_atomic_load(p, __ATOMIC_RELAXED, __HIP_MEMORY_SCOPE_AGENT);
}
__device__ __forceinline__ int ld_cohi(const int* p) {
    return __hip_atomic_load(p, __ATOMIC_RELAXED, __HIP_MEMORY_SCOPE_AGENT);
}
__device__ __forceinline__ void st_cohf(float* p, float v) {
    __hip_atomic_store(p, v, __ATOMIC_RELAXED, __HIP_MEMORY_SCOPE_AGENT);
}
__device__ __forceinline__ void st_cohi(int* p, int v) {
    __hip_atomic_store(p, v, __ATOMIC_RELAXED, __HIP_MEMORY_SCOPE_AGENT);
}
__device__ __forceinline__ int lds_acq(const int* p) {
    return __hip_atomic_load(p, __ATOMIC_ACQUIRE, __HIP_MEMORY_SCOPE_WORKGROUP);
}
__device__ __forceinline__ void lds_rel(int* p, int v) {
    __hip_atomic_store(p, v, __ATOMIC_RELEASE, __HIP_MEMORY_SCOPE_WORKGROUP);
}

// DPP wave_shr1: lane n <- lane n-1; lane 0 <- oldv (bound_ctrl=false keeps old).
__device__ __forceinline__ int dpp_shr1_i(int oldv, int src) {
    return __builtin_amdgcn_update_dpp(oldv, src, 0x138, 0xF, 0xF, false);
}
__device__ __forceinline__ float dpp_shr1_f(float oldv, float src) {
    return __int_as_float(__builtin_amdgcn_update_dpp(
        __float_as_int(oldv), __float_as_int(src), 0x138, 0xF, 0xF, false));
}

__global__ __launch_bounds__(384, 1) void viterbi_r11(
    const float* __restrict__ theta, const float* __restrict__ A,
    float* __restrict__ out, float* __restrict__ bnd, int* __restrict__ prog,
    int* __restrict__ cpG, int* __restrict__ rfG, float* __restrict__ ringG)
{
    // Static LDS in every block (incl. producers) -> guarantees 1 block/CU.
    __shared__ float4 ldsP[8][4][4][64];    // 128 KB: [hc&7][tau][plane][row]
    __shared__ float  recIn[32][8];
    __shared__ float  recOut[32][8];
    __shared__ int    flags[16];

    const int tid  = threadIdx.x;
    const int wv   = tid >> 6;
    const int lane = tid & 63;
    const int bid  = blockIdx.x;

    if (tid < 16) flags[tid] = -1;
    __syncthreads();

    if (bid >= 16) {
        // ===================== producer blocks =====================
        if (wv >= 4) return;                 // waves 4,5 unused here
        const int k     = bid & 7;           // XCD (heuristic)
        const int idx   = (bid - 16) >> 3;   // 0..29 within XCD
        const int s     = 2*k + (idx >= PPS);
        const int pslot = idx % PPS;
        const int u2    = wv;                // tau within hc
        const int row   = s*64 + lane;
        const float4* A4 = (const float4*)A;
        const float4* T4 = (const float4*)theta;
        const int* cp = cpG + s*16;
        for (int h = pslot; h < HCT; h += PPS) {
            while (ld_cohi(cp) < h - DEPTH) __builtin_amdgcn_s_sleep(1);
            const int tau = 4*h + u2;
            int c = tau - lane; c = c < 0 ? 0 : (c > MM-1 ? MM-1 : c);
            const float4* Ar = A4 + ((size_t)row*MM + (size_t)c)*4;
            float4 a0 = Ar[0], a1 = Ar[1], a2 = Ar[2], a3 = Ar[3];
            float4 th = T4[(size_t)row*MM + (size_t)c];
            float4 p0, p1, p2, p3;       // theta-folded exp-domain potentials
            p0.x=exp2f((a0.x+th.x)*LOG2E); p0.y=exp2f((a0.y+th.x)*LOG2E);
            p0.z=exp2f((a0.z+th.x)*LOG2E); p0.w=exp2f((a0.w+th.x)*LOG2E);
            p1.x=exp2f((a1.x+th.y)*LOG2E); p1.y=exp2f((a1.y+th.y)*LOG2E);
            p1.z=exp2f((a1.z+th.y)*LOG2E); p1.w=exp2f((a1.w+th.y)*LOG2E);
            p2.x=exp2f((a2.x+th.z)*LOG2E); p2.y=exp2f((a2.y+th.z)*LOG2E);
            p2.z=exp2f((a2.z+th.z)*LOG2E); p2.w=exp2f((a2.w+th.z)*LOG2E);
            p3.x=exp2f((a3.x+th.w)*LOG2E); p3.y=exp2f((a3.y+th.w)*LOG2E);
            p3.z=exp2f((a3.z+th.w)*LOG2E); p3.w=exp2f((a3.w+th.w)*LOG2E);
            // slot layout matches LDS: float4 index (u2*4+plane)*64 + lane
            float* dst = ringG + ((size_t)(s*DEPTH + (h & (DEPTH-1))) << 12)
                               + (size_t)((u2*4)*64 + lane)*4;
            st_cohf(dst+0,   p0.x); st_cohf(dst+1,   p0.y);
            st_cohf(dst+2,   p0.z); st_cohf(dst+3,   p0.w);
            st_cohf(dst+256, p1.x); st_cohf(dst+257, p1.y);
            st_cohf(dst+258, p1.z); st_cohf(dst+259, p1.w);
            st_cohf(dst+512, p2.x); st_cohf(dst+513, p2.y);
            st_cohf(dst+514, p2.z); st_cohf(dst+515, p2.w);
            st_cohf(dst+768, p3.x); st_cohf(dst+769, p3.y);
            st_cohf(dst+770, p3.z); st_cohf(dst+771, p3.w);
            asm volatile("s_waitcnt vmcnt(0)" ::: "memory");
            if (lane == 0)
                st_cohi(rfG + (size_t)(s*DEPTH + (h & (DEPTH-1)))*16 + u2, h);
        }
        return;
    }

    // ===================== pipeline blocks =====================
    const int strip = ((bid & 7) << 1) | (bid >> 3);   // strip s on XCD s>>1
    const bool isCons = (strip > 0);
    const bool isProd = (strip < 15);

    float* Prec = bnd + (size_t)strip * MM * 8;
    const float* Crec = bnd + (size_t)(strip - 1) * MM * 8;
    int* myflag = prog + strip * 32;
    const int* upflag = prog + (strip - 1) * 32;

    if (wv == 0) {
        // ===================== chain wave (math unchanged R10) ==============
        __builtin_amdgcn_s_setprio(1);
        const int r = lane;
        int   mL = NEGI, mU = NEGI, mD = NEGI;
        float ql0=0,ql1=0,ql2=0,ql3=0;
        float qu0=0,qu1=0,qu2=0,qu3=0;
        float qd0=0,qd1=0,qd2=0,qd3=0;
        if (strip == 0 && lane == 0) { mD = 0; qd0=qd1=qd2=qd3=1.f; }
        if (isCons) {
            while (ld_cohi(upflag) < 1) __builtin_amdgcn_s_sleep(1);
            asm volatile("" ::: "memory");
            qu0 = ld_cohf(Crec+0); qu1 = ld_cohf(Crec+1);
            qu2 = ld_cohf(Crec+2); qu3 = ld_cohf(Crec+3);
            mU  = ld_cohi((const int*)Crec + 4);
        }
        for (int cc = 0; cc < NCH; ++cc) {
            if (isCons) while (lds_acq(&flags[F_RIN]) < cc) {}
            if (isProd) while (lds_acq(&flags[F_OPUB]) < cc - 3) {}
            const int slotBase = (cc & 3) * 8;
#pragma unroll
            for (int half = 0; half < 2; ++half) {
                const int h   = 2*cc + half;
                const int buf = h & 7;
                while (lds_acq(&flags[F_PD + buf]) < h) {}
#pragma unroll
                for (int u2 = 0; u2 < 4; ++u2) {
                    const int u   = half*4 + u2;
                    const int tau = cc*CH + u;
                    const int jq  = tau - r + 1;
                    float4 P0 = ldsP[buf][u2][0][lane];
                    float4 P1 = ldsP[buf][u2][1][lane];
                    float4 P2 = ldsP[buf][u2][2][lane];
                    float4 P3 = ldsP[buf][u2][3][lane];
                    int off = max(max(mD, mU), mL);
                    float sd = ldexpf(1.0f, mD - off);
                    float su = ldexpf(1.0f, mU - off);
                    float sl = ldexpf(1.0f, mL - off);
                    float dm  = fmaf(qd1,P0.y, qd0*P0.x) + fmaf(qd3,P0.w, qd2*P0.z);
                    float dx  = fmaf(qu1,P1.y, qu0*P1.x) + fmaf(qu3,P1.w, qu2*P1.z);
                    float dy  = fmaf(ql1,P2.y, ql0*P2.x) + fmaf(ql3,P2.w, ql2*P2.z);
                    float ds2 = fmaf(qd1,P3.y, qd0*P3.x) + fmaf(qd3,P3.w, qd2*P3.z);
                    float g0 = dm *sd;
                    float g1 = dx *su;
                    float g2 = dy *sl;
                    float g3 = ds2*sd;
                    float gmax = fmaxf(fmaxf(g0,g1), fmaxf(g2,g3));
                    int e = (int)(__float_as_uint(gmax) >> 23) - 126;
                    float qn0 = ldexpf(g0, 1-e), qn1 = ldexpf(g1, 1-e);
                    float qn2 = ldexpf(g2, 1-e), qn3 = ldexpf(g3, 1-e);
                    int   mn  = off + e - 1;
                    const bool valid = (jq >= 1) && (jq <= MM);
                    if (!valid) { qn0=qn1=qn2=qn3=0.f; mn=NEGI; }
                    if (lane == 63) {
                        if (isProd) {
                            *(float4*)&recOut[slotBase + u][0] = make_float4(qn0,qn1,qn2,qn3);
                            recOut[slotBase + u][4] = __int_as_float(mn);
                        } else if (jq == MM) {
                            out[0] = LN2f * ((float)mn + log2f((qn0+qn1)+(qn2+qn3)));
                        }
                    }
                    int bmv = NEGI; float b0=0,b1=0,b2=0,b3=0;
                    if (isCons) {
                        float4 bb = *(const float4*)&recIn[slotBase + u][0];
                        bmv = __float_as_int(recIn[slotBase + u][4]);
                        b0=bb.x; b1=bb.y; b2=bb.z; b3=bb.w;
                    }
                    mD = mU; qd0=qu0; qd1=qu1; qd2=qu2; qd3=qu3;
                    mU  = dpp_shr1_i(bmv, mn);
                    qu0 = dpp_shr1_f(b0, qn0);
                    qu1 = dpp_shr1_f(b1, qn1);
                    qu2 = dpp_shr1_f(b2, qn2);
                    qu3 = dpp_shr1_f(b3, qn3);
                    mL = mn; ql0=qn0; ql1=qn1; ql2=qn2; ql3=qn3;
                }
                if (lane == 0) lds_rel(&flags[F_CDONE], h);
            }
        }
    } else if (wv <= 3) {
        // ===================== loader waves (ring -> LDS) ===================
        const int L = wv - 1;                 // 0..2, handles h == L (mod 3)
        int* cp = cpG + strip*16;
        for (int h = L; h < HCT; h += 3) {
            if (L == 0) st_cohi(cp, lds_acq(&flags[F_CDONE]));  // pace producers
            while (lds_acq(&flags[F_CDONE]) < h - 8) {}         // LDS slot free
            const int slot = h & (DEPTH-1);
            const int buf  = h & 7;
            const int* rf = rfG + (size_t)(strip*DEPTH + slot)*16;
            while (ld_cohi(rf+0) < h || ld_cohi(rf+1) < h ||
                   ld_cohi(rf+2) < h || ld_cohi(rf+3) < h) {}
            asm volatile("" ::: "memory");
            const float* src = ringG + ((size_t)(strip*DEPTH + slot) << 12)
                                     + (size_t)lane*4;
            float4 q[16];
#pragma unroll
            for (int i = 0; i < 16; ++i) {
                const float* sp = src + i*256;
                q[i].x = ld_cohf(sp+0); q[i].y = ld_cohf(sp+1);
                q[i].z = ld_cohf(sp+2); q[i].w = ld_cohf(sp+3);
            }
            float4* dst = &ldsP[buf][0][0][0];
#pragma unroll
            for (int i = 0; i < 16; ++i) dst[i*64 + lane] = q[i];
            lds_rel(&flags[F_PD + buf], h);
        }
        if (L == 0) st_cohi(cp, HCT);         // final pace post
    } else if (wv == 4) {
        // ===================== out-comms wave =====================
        if (!isProd) return;
        const int rec0 = lane / 5, wd0 = lane % 5;
        const int rec1 = (lane+64) / 5, wd1 = (lane+64) % 5;
        const bool on1 = (lane + 64) < 80;
        for (int cc = 0; cc < NCH; cc += 2) {
            while (lds_acq(&flags[F_CDONE]) < 2*cc + 3) __builtin_amdgcn_s_sleep(1);
            {
                int col = 8*(cc + (rec0 >> 3)) + (rec0 & 7) - 62;
                float v = recOut[(cc & 3)*8 + rec0][wd0];
                if (col >= 1 && col <= MM) st_cohf(Prec + (size_t)(col-1)*8 + wd0, v);
            }
            if (on1) {
                int col = 8*(cc + (rec1 >> 3)) + (rec1 & 7) - 62;
                float v = recOut[(cc & 3)*8 + rec1][wd1];
                if (col >= 1 && col <= MM) st_cohf(Prec + (size_t)(col-1)*8 + wd1, v);
            }
            asm volatile("s_waitcnt vmcnt(0)" ::: "memory");
            int done = 8*(cc + 1) - 55; if (done > MM) done = MM;
            if (done >= 1 && lane == 0) st_cohi(myflag, done);
            if (lane == 0) lds_rel(&flags[F_OPUB], cc + 1);
        }
    } else {
        // ===================== in-comms wave =====================
        if (!isCons) return;
        const int rec0 = lane / 5, wd0 = lane % 5;
        const int rec1 = (lane+64) / 5, wd1 = (lane+64) % 5;
        const bool on1 = (lane + 64) < 80;
        for (int cc = 0; cc < NCH; cc += 2) {
            while (lds_acq(&flags[F_CDONE]) < 2*cc - 3) __builtin_amdgcn_s_sleep(1);
            int need = 8*cc + 17; if (need > MM) need = MM;
            while (ld_cohi(upflag) < need) __builtin_amdgcn_s_sleep(1);
            asm volatile("" ::: "memory");
            {
                int col = 8*cc + 2 + rec0; if (col > MM) col = MM;
                float v = ld_cohf(Crec + (size_t)(col-1)*8 + wd0);
                recIn[(cc & 3)*8 + rec0][wd0] = v;
            }
            if (on1) {
                int col = 8*cc + 2 + rec1; if (col > MM) col = MM;
                float v = ld_cohf(Crec + (size_t)(col-1)*8 + wd1);
                recIn[(cc & 3)*8 + rec1][wd1] = v;
            }
            if (lane == 0) lds_rel(&flags[F_RIN], cc + 1);
        }
    }
}

extern "C" void kernel_launch(void* const* d_in, const int* in_sizes, int n_in,
                              void* d_out, int out_size, void* d_ws, size_t ws_size,
                              hipStream_t stream) {
    const float* theta = (const float*)d_in[0];   // [1024,1024,4] f32
    const float* A     = (const float*)d_in[1];   // [1024,1024,4,4] f32
    float* out = (float*)d_out;                   // [1] f32
    // ws layout (0xAA poison -> all flags/counters negative -> safe spins):
    //   [0, 512K)        boundary records [16][1024][8] f32
    //   [512K, 512K+4K)  record progress flags prog[16*32]
    //   [+4K, +8K)       chain progress cpG[16*16] (one 64B line per strip)
    //   [+8K, +40K)      ring flags rfG[16*32*16] (one 64B line per slot)
    //   [64K-aligned 8M) P ring ringG: 16 strips * 32 slots * 16 KB
    char* base = (char*)d_ws;
    float* bnd  = (float*)base;
    int*   prog = (int*)(base + (size_t)512*1024);
    int*   cpG  = (int*)(base + (size_t)512*1024 + 4*1024);
    int*   rfG  = (int*)(base + (size_t)512*1024 + 8*1024);
    float* ring = (float*)(base + (size_t)512*1024 + 64*1024);
    viterbi_r11<<<256, 384, 0, stream>>>(theta, A, out, bnd, prog, cpG, rfG, ring);
}